// Round 3
// baseline (257.956 us; speedup 1.0000x reference)
//
#include <hip/hip_runtime.h>

// ---------------------------------------------------------------------------
// TripletContrastiveLoss on MI355X (gfx950)  — Round 15
// Post-mortem R13/R14: kernel is LATENCY-bound (all pipes <35%); occupancy
// (waves/SIMD 4->2) tracked the regressions exactly. Every scheme that buys
// pipeline depth with LDS/VGPR loses the TLP doing the real latency hiding.
// This round REMOVES the LDS path entirely from tile_mindist:
//   * fragments load DIRECTLY global->VGPR: the MFMA frag pattern (l15->row,
//     quad->16B chunk) touches 16 x 64B fully-consumed lines per instr — the
//     same line count as a coalesced 1KB load. G (16 MB) is L3/L2-resident.
//   * double-buffered frag registers, prefetch distance 2, 32-step FULL
//     unroll -> all K-offsets are 13-bit immediates, ZERO address VALU and
//     ZERO barriers in the loop; compiler emits counted vmcnt per-register.
//   * no LDS (0 B), no __syncthreads anywhere in the K-loop; waves fully
//     independent -> ~12 independent waves/CU of pure TLP.
// Operand addressing provably reproduces the prior LDS contents; epilogue and
// kernels 0/1/3 + launcher are byte-identical to the validated R14 versions.
// ---------------------------------------------------------------------------

#define B_ROWS 8192
#define DIM    1024

typedef __bf16 bf16x8 __attribute__((ext_vector_type(8)));
typedef float  f32x4  __attribute__((ext_vector_type(4)));

__device__ __forceinline__ unsigned short f2bf_rne(float x) {
    unsigned u = __float_as_uint(x);
    unsigned r = (u + 0x7FFFu + ((u >> 16) & 1u)) >> 16;
    return (unsigned short)r;
}
__device__ __forceinline__ float bf2f(unsigned short h) {
    return __uint_as_float(((unsigned)h) << 16);
}

// ---------------------------------------------------------------------------
// Kernel 0: slot assignment. 1 block x 256 threads, 32 rows/thread, rows
// enumerated t + 256*i (lane-coalesced). Wave-0 shuffle scan for the prefix.
// cnt[0] = nA. slotOf overlays posmin (clobbered later by 0xFF memset).
// (validated R13/R14, absmax 0)
// ---------------------------------------------------------------------------
__global__ __launch_bounds__(256) void compute_slots(
    const int* __restrict__ dom, int* __restrict__ slotOf,
    unsigned* __restrict__ cnt)
{
    __shared__ int cnts[256];
    __shared__ int base[257];
    const int t = threadIdx.x;

    unsigned mask = 0u; int c = 0;
    #pragma unroll
    for (int i = 0; i < 32; ++i) {
        const int isA = (dom[t + 256 * i] == 0) ? 1 : 0;
        mask |= ((unsigned)isA) << i;
        c += isA;
    }
    cnts[t] = c;
    __syncthreads();
    if (t < 64) {   // wave 0: 4 counts/lane, inclusive shuffle scan
        const int c0 = cnts[4 * t + 0], c1 = cnts[4 * t + 1];
        const int c2 = cnts[4 * t + 2], c3 = cnts[4 * t + 3];
        const int s4 = c0 + c1 + c2 + c3;
        int sc = s4;
        #pragma unroll
        for (int d = 1; d < 64; d <<= 1) {
            const int o = __shfl_up(sc, d);
            if (t >= d) sc += o;
        }
        const int b = sc - s4;                  // exclusive prefix
        base[4 * t + 0] = b;
        base[4 * t + 1] = b + c0;
        base[4 * t + 2] = b + c0 + c1;
        base[4 * t + 3] = b + c0 + c1 + c2;
        if (t == 63) { base[256] = sc; cnt[0] = (unsigned)sc; }  // nA
    }
    __syncthreads();
    const int nA = base[256];
    int aB = base[t];
    int fB = nA + t * 32 - base[t];   // F rows before thread t in (t,i) order
    #pragma unroll
    for (int i = 0; i < 32; ++i) {
        const int isA = (mask >> i) & 1;
        slotOf[t + 256 * i] = isA ? aB : fB;
        aB += isA;
        fB += 1 - isA;
    }
}

// ---------------------------------------------------------------------------
// Kernel 1: one row per WAVE. 2048 blocks x 256 threads (4 waves). Wave-local
// shuffle reductions only. L2-normalize fp32, round to bf16, scatter to slot.
// sqG[slot] = sum of squares of the bf16-ROUNDED row.  (unchanged)
// ---------------------------------------------------------------------------
__global__ __launch_bounds__(256) void normalize_rows(
    const float* __restrict__ feat, const int* __restrict__ labels,
    const int* __restrict__ slotOf, unsigned short* __restrict__ G,
    int* __restrict__ labG, float* __restrict__ sqG)
{
    const int wv = threadIdx.x >> 6, lane = threadIdx.x & 63;
    const int row = blockIdx.x * 4 + wv;

    const float4* src = (const float4*)(feat + (size_t)row * DIM);
    float4 v[4];
    float ss = 0.0f;
    #pragma unroll
    for (int j = 0; j < 4; ++j) {
        v[j] = src[j * 64 + lane];
        ss += v[j].x * v[j].x + v[j].y * v[j].y + v[j].z * v[j].z + v[j].w * v[j].w;
    }
    #pragma unroll
    for (int s = 32; s > 0; s >>= 1) ss += __shfl_xor(ss, s);
    const float inv = 1.0f / fmaxf(sqrtf(ss), 1e-12f);

    const int slot = slotOf[row];
    unsigned short ub[16];
    float ss2 = 0.0f;
    #pragma unroll
    for (int j = 0; j < 4; ++j) {
        const float f0 = v[j].x * inv, f1 = v[j].y * inv,
                    f2 = v[j].z * inv, f3 = v[j].w * inv;
        ub[j * 4 + 0] = f2bf_rne(f0); ub[j * 4 + 1] = f2bf_rne(f1);
        ub[j * 4 + 2] = f2bf_rne(f2); ub[j * 4 + 3] = f2bf_rne(f3);
        #pragma unroll
        for (int q = 0; q < 4; ++q) {
            const float fr = bf2f(ub[j * 4 + q]);
            ss2 += fr * fr;
        }
    }
    #pragma unroll
    for (int s = 32; s > 0; s >>= 1) ss2 += __shfl_xor(ss2, s);
    if (lane == 0) {
        sqG[slot]  = ss2;
        labG[slot] = labels[row];
    }
    ushort4* dst = (ushort4*)(G + (size_t)slot * DIM);
    #pragma unroll
    for (int j = 0; j < 4; ++j) {
        ushort4 pk;
        pk.x = ub[j * 4 + 0]; pk.y = ub[j * 4 + 1];
        pk.z = ub[j * 4 + 2]; pk.w = ub[j * 4 + 3];
        dst[j * 64 + lane] = pk;
    }
}

// ---------------------------------------------------------------------------
// Kernel 2: 128x128 tiles, 4 waves (each 64x64 via 4x4 of 16x16x32 bf16
// MFMA), K=1024 in 32 steps of BK=32 — NO LDS, NO BARRIERS.
// Each lane loads its own MFMA fragments straight from G:
//   addr = (row0 + l15 + fm*16)*2048 + step*64 + quad*16
// i.e. 16 rows x 64 B per load instruction, every byte consumed. Fragment
// contents are bit-identical to what the old LDS path staged.
// Double-buffered frag regs, prefetch distance 2: step s consumes frags
// loaded at s-2; loads for s+2 reuse the buffer right after its MFMAs.
// Full 32-step unroll -> all offsets are immediates (max 1984 < 4096).
// Epilogue: min d^2 per anchor row -> atomicMin (uint order). (unchanged)
// ---------------------------------------------------------------------------
__global__ __launch_bounds__(256) void tile_mindist(
    const unsigned short* __restrict__ G, const int* __restrict__ labG,
    const float* __restrict__ sqG, const unsigned* __restrict__ cnt,
    unsigned* __restrict__ posmin, unsigned* __restrict__ negmin)
{
    const int nA = (int)cnt[0];
    const int nF = B_ROWS - nA;
    const int nTA = (nA + 127) >> 7;
    const int nTF = (nF + 127) >> 7;
    const int total = nTA * nTF;

    const int t = threadIdx.x;
    const int lane = t & 63, w = t >> 6;
    const int wm = w >> 1, wn = w & 1;          // wave sub-tile coords (x64)
    const int l15 = lane & 15, quad = lane >> 4;

    const char* Gb = (const char*)G;

    for (int tile = blockIdx.x; tile < total; tile += gridDim.x) {
        const int tx = tile % nTA;
        const int ty = tile / nTA;
        const int rowA0 = tx * 128;
        const int rowF0 = nA + ty * 128;

        // Per-lane fragment base pointers (clamped to the last row; clamped
        // lanes produce junk dots that the epilogue's va/vf masks discard).
        const char* pA[4]; const char* pF[4];
        #pragma unroll
        for (int q = 0; q < 4; ++q) {
            int ra = rowA0 + wm * 64 + q * 16 + l15;
            if (ra > B_ROWS - 1) ra = B_ROWS - 1;
            int rf = rowF0 + wn * 64 + q * 16 + l15;
            if (rf > B_ROWS - 1) rf = B_ROWS - 1;
            pA[q] = Gb + (size_t)ra * (DIM * 2) + quad * 16;
            pF[q] = Gb + (size_t)rf * (DIM * 2) + quad * 16;
        }

        f32x4 acc[4][4] = {};
        bf16x8 fa[2][4], fb[2][4];

        // Prologue: load steps 0 and 1 into the two frag buffers.
        #pragma unroll
        for (int q = 0; q < 4; ++q) {
            fa[0][q] = *(const bf16x8*)(pA[q]);
            fb[0][q] = *(const bf16x8*)(pF[q]);
            fa[1][q] = *(const bf16x8*)(pA[q] + 64);
            fb[1][q] = *(const bf16x8*)(pF[q] + 64);
        }

        #pragma unroll
        for (int step = 0; step < 32; ++step) {
            const int cur = step & 1;           // constant after full unroll
            #pragma unroll
            for (int fm = 0; fm < 4; ++fm)
                #pragma unroll
                for (int fn = 0; fn < 4; ++fn)
                    acc[fm][fn] = __builtin_amdgcn_mfma_f32_16x16x32_bf16(
                        fa[cur][fm], fb[cur][fn], acc[fm][fn], 0, 0, 0);
            if (step + 2 < 32) {                // refill the buffer just read
                #pragma unroll
                for (int q = 0; q < 4; ++q) {
                    fa[cur][q] = *(const bf16x8*)(pA[q] + (step + 2) * 64);
                    fb[cur][q] = *(const bf16x8*)(pF[q] + (step + 2) * 64);
                }
            }
        }

        // Epilogue. C/D layout: col = lane&15 (field), row = quad*4+reg.
        const float INFV = __uint_as_float(0x7f800000u);
        float sqf[4]; int lf_[4]; bool vf[4];
        #pragma unroll
        for (int fn = 0; fn < 4; ++fn) {
            const int rf = rowF0 + wn * 64 + fn * 16 + l15;
            vf[fn] = rf < B_ROWS;
            const int rc = vf[fn] ? rf : (B_ROWS - 1);
            sqf[fn] = sqG[rc];
            lf_[fn] = labG[rc];
        }
        #pragma unroll
        for (int fm = 0; fm < 4; ++fm) {
            #pragma unroll
            for (int r = 0; r < 4; ++r) {
                const int ra = rowA0 + wm * 64 + fm * 16 + quad * 4 + r;
                const bool va = ra < nA;
                const int rac = va ? ra : 0;
                const float sqa = sqG[rac];
                const int la_ = labG[rac];
                float pmin = INFV, nmin = INFV;
                #pragma unroll
                for (int fn = 0; fn < 4; ++fn) {
                    const float dd = fmaxf(sqa + sqf[fn] - 2.0f * acc[fm][fn][r], 0.0f);
                    if (vf[fn]) {
                        if (la_ == lf_[fn]) pmin = fminf(pmin, dd);
                        else                nmin = fminf(nmin, dd);
                    }
                }
                #pragma unroll
                for (int s = 1; s < 16; s <<= 1) {
                    pmin = fminf(pmin, __shfl_xor(pmin, s));
                    nmin = fminf(nmin, __shfl_xor(nmin, s));
                }
                if (l15 == 0 && va) {
                    if (pmin < INFV) atomicMin(&posmin[ra], __float_as_uint(pmin));
                    if (nmin < INFV) atomicMin(&negmin[ra], __float_as_uint(nmin));
                }
            }
        }
        // No barriers needed between tiles: no shared state.
    }
}

// ---------------------------------------------------------------------------
// Kernel 3: sqrt(d^2 mins) + hinge + sum/count. Untouched slots stay
// 0xFFFFFFFF and drop out as invalid.  (unchanged)
// ---------------------------------------------------------------------------
__global__ __launch_bounds__(256) void reduce_loss(
    const unsigned* __restrict__ posmin, const unsigned* __restrict__ negmin,
    float* __restrict__ accum)
{
    const int i = blockIdx.x * 256 + threadIdx.x;
    const unsigned up = posmin[i], un = negmin[i];
    float tl = 0.0f, c = 0.0f;
    if (up != 0xFFFFFFFFu && un != 0xFFFFFFFFu) {
        const float pd = sqrtf(__uint_as_float(up));
        const float nd = sqrtf(__uint_as_float(un));
        tl = fmaxf(pd - nd + 0.3f, 0.0f);
        c = 1.0f;
    }
    #pragma unroll
    for (int s = 32; s > 0; s >>= 1) {
        tl += __shfl_down(tl, s);
        c  += __shfl_down(c, s);
    }
    __shared__ float sb[8];
    const int lane = threadIdx.x & 63, w = threadIdx.x >> 6;
    if (lane == 0) { sb[w] = tl; sb[4 + w] = c; }
    __syncthreads();
    if (threadIdx.x == 0) {
        atomicAdd(&accum[0], sb[0] + sb[1] + sb[2] + sb[3]);
        atomicAdd(&accum[1], sb[4] + sb[5] + sb[6] + sb[7]);
    }
}

__global__ void finalize(const float* __restrict__ accum, float* __restrict__ out) {
    const float s = accum[0], c = accum[1];
    out[0] = (c > 0.0f) ? s / fmaxf(c, 1.0f) : 0.0f;
}

// ---------------------------------------------------------------------------
extern "C" void kernel_launch(void* const* d_in, const int* in_sizes, int n_in,
                              void* d_out, int out_size, void* d_ws, size_t ws_size,
                              hipStream_t stream) {
    const float* feat  = (const float*)d_in[0];
    const int* labels  = (const int*)d_in[1];
    const int* dom     = (const int*)d_in[2];
    float* out = (float*)d_out;

    char* ws = (char*)d_ws;
    // Workspace layout (bytes) — identical footprint to validated R4/R8 layout:
    unsigned short* G   = (unsigned short*)(ws);                 // 16,777,216
    int*      labG      = (int*)(ws + 16777216);                 //     32,768
    float*    sqG       = (float*)(ws + 16809984);               //     32,768
    unsigned* posmin    = (unsigned*)(ws + 16842752);            //     32,768
    unsigned* negmin    = (unsigned*)(ws + 16875520);            //     32,768
    unsigned* cnt       = (unsigned*)(ws + 16908288);            //  8 (nA)
    float*    accum     = (float*)(ws + 16908296);               //  8 (sum, count)
    // slotOf OVERLAYS posmin: written by compute_slots, consumed by
    // normalize_rows, then clobbered by the 0xFF memset (stream-ordered).
    int*      slotOf    = (int*)(ws + 16842752);

    hipMemsetAsync(cnt, 0, 16, stream);             // cnt + accum = 0

    compute_slots<<<1, 256, 0, stream>>>(dom, slotOf, cnt);
    normalize_rows<<<B_ROWS / 4, 256, 0, stream>>>(feat, labels, slotOf,
                                                   G, labG, sqG);

    hipMemsetAsync(posmin, 0xFF, 65536, stream);    // posmin+negmin = +inf bits

    // Max tiles over all nA splits: ceil(a/128)*ceil((8192-a)/128) <= 1056.
    tile_mindist<<<1056, 256, 0, stream>>>(G, labG, sqG, cnt, posmin, negmin);

    reduce_loss<<<B_ROWS / 256, 256, 0, stream>>>(posmin, negmin, accum);
    finalize<<<1, 1, 0, stream>>>(accum, out);
}

// Round 4
// 170.112 us; speedup vs baseline: 1.5164x; 1.5164x over previous
//
#include <hip/hip_runtime.h>

// ---------------------------------------------------------------------------
// TripletContrastiveLoss on MI355X (gfx950)  — Round 16
// R13/R14/R15 all regressed vs the R12 skeleton -> R12's structure is a local
// optimum on every axis perturbed. This round restores R12's tile_mindist
// EXACTLY (K-loop/epilogue byte-identical) and changes only:
//  (1) tile->(tx,ty) mapping: bijective per-XCD rectangle decomposition
//      (xcd = blockIdx&7 -> 2 tx-bands x 4 ty-bands, ty-fast sweep).
//      R12's FETCH_SIZE=103MB = 6.4x G: consecutive tiles shared an F-panel
//      across 8 non-coherent XCD L2s (round-robin dispatch) -> 8x refetch.
//      Rectangle keeps 1 hot A-panel (256KB) + F-band (~2MB) per XCD L2.
//  (2) dispatch fusion: memsets folded into compute_slots/normalize_rows;
//      finalize fused into reduce_loss via device-scope ticket. 7 -> 4
//      dispatches (~82 us constant non-tile share shrinks).
// ---------------------------------------------------------------------------

#define B_ROWS 8192
#define DIM    1024

typedef __bf16 bf16x8 __attribute__((ext_vector_type(8)));
typedef float  f32x4  __attribute__((ext_vector_type(4)));

__device__ __forceinline__ unsigned short f2bf_rne(float x) {
    unsigned u = __float_as_uint(x);
    unsigned r = (u + 0x7FFFu + ((u >> 16) & 1u)) >> 16;
    return (unsigned short)r;
}
__device__ __forceinline__ float bf2f(unsigned short h) {
    return __uint_as_float(((unsigned)h) << 16);
}

// Async global->LDS, 16 B per lane. LDS dest is wave-uniform base; HW places
// lane i at base + 16*i (matches 16 rows x 64 B chunk layout).
__device__ __forceinline__ void async_copy16(const void* g, void* l) {
    __builtin_amdgcn_global_load_lds(
        (const __attribute__((address_space(1))) unsigned int*)g,
        (__attribute__((address_space(3))) unsigned int*)l,
        16, 0, 0);
}

// ---------------------------------------------------------------------------
// Kernel 0: slot assignment (validated R13-R15, absmax 0) + init of the
// accumulator/ticket words (replaces hipMemsetAsync(cnt,0,16)).
// slotOf overlays posmin; normalize_rows consumes it then re-inits to 0xFF.
// ---------------------------------------------------------------------------
__global__ __launch_bounds__(256) void compute_slots(
    const int* __restrict__ dom, int* __restrict__ slotOf,
    unsigned* __restrict__ cnt, float* __restrict__ accum)
{
    __shared__ int cnts[256];
    __shared__ int base[257];
    const int t = threadIdx.x;

    if (t == 0) {                       // replaces the 16-byte memset
        cnt[1] = 0u;                    // reduce_loss ticket
        accum[0] = 0.0f;                // loss sum
        accum[1] = 0.0f;                // valid count
    }

    unsigned mask = 0u; int c = 0;
    #pragma unroll
    for (int i = 0; i < 32; ++i) {
        const int isA = (dom[t + 256 * i] == 0) ? 1 : 0;
        mask |= ((unsigned)isA) << i;
        c += isA;
    }
    cnts[t] = c;
    __syncthreads();
    if (t < 64) {   // wave 0: 4 counts/lane, inclusive shuffle scan
        const int c0 = cnts[4 * t + 0], c1 = cnts[4 * t + 1];
        const int c2 = cnts[4 * t + 2], c3 = cnts[4 * t + 3];
        const int s4 = c0 + c1 + c2 + c3;
        int sc = s4;
        #pragma unroll
        for (int d = 1; d < 64; d <<= 1) {
            const int o = __shfl_up(sc, d);
            if (t >= d) sc += o;
        }
        const int b = sc - s4;                  // exclusive prefix
        base[4 * t + 0] = b;
        base[4 * t + 1] = b + c0;
        base[4 * t + 2] = b + c0 + c1;
        base[4 * t + 3] = b + c0 + c1 + c2;
        if (t == 63) { base[256] = sc; cnt[0] = (unsigned)sc; }  // nA
    }
    __syncthreads();
    const int nA = base[256];
    int aB = base[t];
    int fB = nA + t * 32 - base[t];   // F rows before thread t in (t,i) order
    #pragma unroll
    for (int i = 0; i < 32; ++i) {
        const int isA = (mask >> i) & 1;
        slotOf[t + 256 * i] = isA ? aB : fB;
        aB += isA;
        fB += 1 - isA;
    }
}

// ---------------------------------------------------------------------------
// Kernel 1: one row per WAVE. 2048 blocks x 256 threads (4 waves). L2-norm
// fp32 -> bf16, scatter to slot. sqG[slot] = sum sq of the ROUNDED row.
// NEW: after consuming slotOf[row] (same address as posmin[row] — same-
// address dependence orders the write), re-init posmin[row]=negmin[row]=0xFF,
// replacing the 64 KiB memset dispatch. Every row index is written exactly
// once, so all 8192 slots are covered.
// ---------------------------------------------------------------------------
__global__ __launch_bounds__(256) void normalize_rows(
    const float* __restrict__ feat, const int* __restrict__ labels,
    int* slotOf /* aliases posmin */, unsigned* __restrict__ negmin,
    unsigned short* __restrict__ G, int* __restrict__ labG,
    float* __restrict__ sqG)
{
    const int wv = threadIdx.x >> 6, lane = threadIdx.x & 63;
    const int row = blockIdx.x * 4 + wv;

    const float4* src = (const float4*)(feat + (size_t)row * DIM);
    float4 v[4];
    float ss = 0.0f;
    #pragma unroll
    for (int j = 0; j < 4; ++j) {
        v[j] = src[j * 64 + lane];
        ss += v[j].x * v[j].x + v[j].y * v[j].y + v[j].z * v[j].z + v[j].w * v[j].w;
    }
    #pragma unroll
    for (int s = 32; s > 0; s >>= 1) ss += __shfl_xor(ss, s);
    const float inv = 1.0f / fmaxf(sqrtf(ss), 1e-12f);

    const int slot = slotOf[row];
    if (lane == 0) {                       // re-init AFTER the read (overlay)
        ((unsigned*)slotOf)[row] = 0xFFFFFFFFu;   // posmin[row] = +inf bits
        negmin[row] = 0xFFFFFFFFu;
    }
    unsigned short ub[16];
    float ss2 = 0.0f;
    #pragma unroll
    for (int j = 0; j < 4; ++j) {
        const float f0 = v[j].x * inv, f1 = v[j].y * inv,
                    f2 = v[j].z * inv, f3 = v[j].w * inv;
        ub[j * 4 + 0] = f2bf_rne(f0); ub[j * 4 + 1] = f2bf_rne(f1);
        ub[j * 4 + 2] = f2bf_rne(f2); ub[j * 4 + 3] = f2bf_rne(f3);
        #pragma unroll
        for (int q = 0; q < 4; ++q) {
            const float fr = bf2f(ub[j * 4 + q]);
            ss2 += fr * fr;
        }
    }
    #pragma unroll
    for (int s = 32; s > 0; s >>= 1) ss2 += __shfl_xor(ss2, s);
    if (lane == 0) {
        sqG[slot]  = ss2;
        labG[slot] = labels[row];
    }
    ushort4* dst = (ushort4*)(G + (size_t)slot * DIM);
    #pragma unroll
    for (int j = 0; j < 4; ++j) {
        ushort4 pk;
        pk.x = ub[j * 4 + 0]; pk.y = ub[j * 4 + 1];
        pk.z = ub[j * 4 + 2]; pk.w = ub[j * 4 + 3];
        dst[j * 64 + lane] = pk;
    }
}

// ---------------------------------------------------------------------------
// Kernel 2: persistent 128x128 tiles, 4 waves (each 64x64 via 4x4 of
// 16x16x32 bf16 MFMA), K=1024 in 32 steps of BK=32. K-loop/epilogue are
// byte-identical to the validated 93 µs R12 kernel. ONLY the tile->(tx,ty)
// mapping changed: per-XCD rectangles.
//   xcd = blockIdx&7; tx-bands of 2 (bx=xcd&1), ty-bands of 4 (by=xcd>>1);
//   within a rectangle sweep ty FAST -> one A-panel (256 KB) stays hot while
//   the F-band (<=~2.25 MB) stays L2-resident across tx iterations.
// Bijective for any nA: band sizes q/q+1, empty bands contribute nothing,
// sum over bands covers every (tx,ty) exactly once. Grid 1056 = 8 x 132:
// block b serves local indices j = b>>3, b>>3 + 132, ...
// ---------------------------------------------------------------------------
__global__ __launch_bounds__(256) void tile_mindist(
    const unsigned short* __restrict__ G, const int* __restrict__ labG,
    const float* __restrict__ sqG, const unsigned* __restrict__ cnt,
    unsigned* __restrict__ posmin, unsigned* __restrict__ negmin)
{
    const int nA = (int)cnt[0];
    const int nF = B_ROWS - nA;
    const int nTA = (nA + 127) >> 7;
    const int nTF = (nF + 127) >> 7;

    // [buf][A=0/F=1][128 rows x 32 shorts (64 B, unpadded)] = 32,768 B
    __shared__ __align__(16) unsigned short S[2][2][128 * 32];

    const int t = threadIdx.x;
    const int lane = t & 63, w = t >> 6;
    const int wm = w >> 1, wn = w & 1;          // wave sub-tile coords (x64)
    const int l15 = lane & 15, quad = lane >> 4;

    // Async staging geometry: chunk ch = rows [16ch, 16ch+16); wave w owns
    // chunks 2w and 2w+1 of both arrays. Lane: row 16ch + (lane>>2),
    // byte col (lane&3)*16. LDS base per chunk is wave-uniform.
    const int ch0 = 2 * w;
    const int crow = lane >> 2;
    const int cbyte = (lane & 3) * 16;

    // Fragment read offsets (shorts), row stride 32 shorts.
    const int rdA = (wm * 64 + l15) * 32 + quad * 8;
    const int rdF = (wn * 64 + l15) * 32 + quad * 8;

    const char* Gb = (const char*)G;

    // ---- per-XCD rectangle mapping ----
    const int xcd = blockIdx.x & 7;
    const int bx  = xcd & 1;                    // tx band (2)
    const int by  = xcd >> 1;                   // ty band (4)
    const int qa = nTA >> 1, ra = nTA & 1;
    const int sa = qa + ((bx < ra) ? 1 : 0);
    const int xa = bx * qa + ((bx < ra) ? bx : ra);
    const int qf = nTF >> 2, rf = nTF & 3;
    const int sf = qf + ((by < rf) ? 1 : 0);
    const int ya = by * qf + ((by < rf) ? by : rf);
    const int localN = sa * sf;
    const int j0 = blockIdx.x >> 3;             // 0..131
    const int jstride = (int)(gridDim.x >> 3);  // 132

    for (int j = j0; j < localN; j += jstride) {
        const int tx = xa + j / sf;             // slow: A-panel
        const int ty = ya + j % sf;             // fast: sweep F-band
        const int rowA0 = tx * 128;
        const int rowF0 = nA + ty * 128;

        const char* ga[2]; const char* gf[2];
        #pragma unroll
        for (int h = 0; h < 2; ++h) {
            const int ch = ch0 + h;
            const int rA = rowA0 + 16 * ch + crow;          // < 8192 always
            int rF = rowF0 + 16 * ch + crow;
            if (rF > B_ROWS - 1) rF = B_ROWS - 1;           // clamp; masked later
            ga[h] = Gb + (size_t)rA * (DIM * 2) + cbyte;
            gf[h] = Gb + (size_t)rF * (DIM * 2) + cbyte;
        }

        f32x4 acc[4][4] = {};

        // Prologue: stage K-chunk 0 into buffer 0.
        #pragma unroll
        for (int h = 0; h < 2; ++h) {
            async_copy16(ga[h], &S[0][0][(ch0 + h) * 512]);
            async_copy16(gf[h], &S[0][1][(ch0 + h) * 512]);
        }
        __syncthreads();                         // drains vmcnt (buf0 ready)

        #pragma unroll 4
        for (int step = 0; step < 32; ++step) {
            const int cur = step & 1;
            const int nb = cur ^ 1;
            if (step < 31) {                     // async-stage step+1 into nb
                const int off = (step + 1) * 64; // 64 B of K per step
                #pragma unroll
                for (int h = 0; h < 2; ++h) {
                    async_copy16(ga[h] + off, &S[nb][0][(ch0 + h) * 512]);
                    async_copy16(gf[h] + off, &S[nb][1][(ch0 + h) * 512]);
                }
            }

            const unsigned short* pa = &S[cur][0][rdA];
            const unsigned short* pf = &S[cur][1][rdF];
            bf16x8 a[4], b[4];
            #pragma unroll
            for (int fm = 0; fm < 4; ++fm) a[fm] = *(const bf16x8*)(pa + fm * 512);
            #pragma unroll
            for (int fn = 0; fn < 4; ++fn) b[fn] = *(const bf16x8*)(pf + fn * 512);
            #pragma unroll
            for (int fm = 0; fm < 4; ++fm)
                #pragma unroll
                for (int fn = 0; fn < 4; ++fn)
                    acc[fm][fn] = __builtin_amdgcn_mfma_f32_16x16x32_bf16(
                        a[fm], b[fn], acc[fm][fn], 0, 0, 0);

            __syncthreads();   // one barrier: completes nb loads, frees cur
        }

        // Epilogue. C/D layout: col = lane&15 (field), row = quad*4+reg.
        const float INFV = __uint_as_float(0x7f800000u);
        float sqf[4]; int lf_[4]; bool vf[4];
        #pragma unroll
        for (int fn = 0; fn < 4; ++fn) {
            const int rf2 = rowF0 + wn * 64 + fn * 16 + l15;
            vf[fn] = rf2 < B_ROWS;
            const int rc = vf[fn] ? rf2 : (B_ROWS - 1);
            sqf[fn] = sqG[rc];
            lf_[fn] = labG[rc];
        }
        #pragma unroll
        for (int fm = 0; fm < 4; ++fm) {
            #pragma unroll
            for (int r = 0; r < 4; ++r) {
                const int ra = rowA0 + wm * 64 + fm * 16 + quad * 4 + r;
                const bool va = ra < nA;
                const int rac = va ? ra : 0;
                const float sqa = sqG[rac];
                const int la_ = labG[rac];
                float pmin = INFV, nmin = INFV;
                #pragma unroll
                for (int fn = 0; fn < 4; ++fn) {
                    const float dd = fmaxf(sqa + sqf[fn] - 2.0f * acc[fm][fn][r], 0.0f);
                    if (vf[fn]) {
                        if (la_ == lf_[fn]) pmin = fminf(pmin, dd);
                        else                nmin = fminf(nmin, dd);
                    }
                }
                #pragma unroll
                for (int s = 1; s < 16; s <<= 1) {
                    pmin = fminf(pmin, __shfl_xor(pmin, s));
                    nmin = fminf(nmin, __shfl_xor(nmin, s));
                }
                if (l15 == 0 && va) {
                    if (pmin < INFV) atomicMin(&posmin[ra], __float_as_uint(pmin));
                    if (nmin < INFV) atomicMin(&negmin[ra], __float_as_uint(nmin));
                }
            }
        }
        __syncthreads();   // protect LDS before next tile's prologue writes
    }
}

// ---------------------------------------------------------------------------
// Kernel 3: sqrt(d^2 mins) + hinge + sum/count, with finalize FUSED via a
// device-scope ticket: the 32nd block to finish publishes the loss.
// atomicAdd is device-scope on gfx950 (cross-XCD coherent); threadfence
// releases the accum adds before the ticket add; the winner re-reads accum
// through atomics (coherent L2 path).
// ---------------------------------------------------------------------------
__global__ __launch_bounds__(256) void reduce_loss(
    const unsigned* __restrict__ posmin, const unsigned* __restrict__ negmin,
    float* __restrict__ accum, unsigned* __restrict__ cnt,
    float* __restrict__ out)
{
    const int i = blockIdx.x * 256 + threadIdx.x;
    const unsigned up = posmin[i], un = negmin[i];
    float tl = 0.0f, c = 0.0f;
    if (up != 0xFFFFFFFFu && un != 0xFFFFFFFFu) {
        const float pd = sqrtf(__uint_as_float(up));
        const float nd = sqrtf(__uint_as_float(un));
        tl = fmaxf(pd - nd + 0.3f, 0.0f);
        c = 1.0f;
    }
    #pragma unroll
    for (int s = 32; s > 0; s >>= 1) {
        tl += __shfl_down(tl, s);
        c  += __shfl_down(c, s);
    }
    __shared__ float sb[8];
    const int lane = threadIdx.x & 63, w = threadIdx.x >> 6;
    if (lane == 0) { sb[w] = tl; sb[4 + w] = c; }
    __syncthreads();
    if (threadIdx.x == 0) {
        atomicAdd(&accum[0], sb[0] + sb[1] + sb[2] + sb[3]);
        atomicAdd(&accum[1], sb[4] + sb[5] + sb[6] + sb[7]);
        __threadfence();
        const unsigned ticket = atomicAdd(&cnt[1], 1u);
        if (ticket == 31u) {               // last of the 32 blocks
            __threadfence();
            const float s2 = atomicAdd(&accum[0], 0.0f);
            const float c2 = atomicAdd(&accum[1], 0.0f);
            out[0] = (c2 > 0.0f) ? s2 / fmaxf(c2, 1.0f) : 0.0f;
        }
    }
}

// ---------------------------------------------------------------------------
extern "C" void kernel_launch(void* const* d_in, const int* in_sizes, int n_in,
                              void* d_out, int out_size, void* d_ws, size_t ws_size,
                              hipStream_t stream) {
    const float* feat  = (const float*)d_in[0];
    const int* labels  = (const int*)d_in[1];
    const int* dom     = (const int*)d_in[2];
    float* out = (float*)d_out;

    char* ws = (char*)d_ws;
    // Workspace layout (bytes) — identical footprint to validated R4/R8 layout:
    unsigned short* G   = (unsigned short*)(ws);                 // 16,777,216
    int*      labG      = (int*)(ws + 16777216);                 //     32,768
    float*    sqG       = (float*)(ws + 16809984);               //     32,768
    unsigned* posmin    = (unsigned*)(ws + 16842752);            //     32,768
    unsigned* negmin    = (unsigned*)(ws + 16875520);            //     32,768
    unsigned* cnt       = (unsigned*)(ws + 16908288);            //  8 (nA, ticket)
    float*    accum     = (float*)(ws + 16908296);               //  8 (sum, count)
    // slotOf OVERLAYS posmin: written by compute_slots, consumed and then
    // re-initialized to 0xFF in-place by normalize_rows (same-address order).
    int*      slotOf    = (int*)(ws + 16842752);

    compute_slots<<<1, 256, 0, stream>>>(dom, slotOf, cnt, accum);
    normalize_rows<<<B_ROWS / 4, 256, 0, stream>>>(feat, labels, slotOf,
                                                   negmin, G, labG, sqG);

    // Grid 1056 = 8 XCD groups x 132; covers max ceil/floor band products.
    tile_mindist<<<1056, 256, 0, stream>>>(G, labG, sqG, cnt, posmin, negmin);

    reduce_loss<<<B_ROWS / 256, 256, 0, stream>>>(posmin, negmin, accum, cnt, out);
}